// Round 4
// baseline (104.326 us; speedup 1.0000x reference)
//
#include <hip/hip_runtime.h>

#define NB 8
#define IN_HW 512
#define OHW 128
#define VOLD 128

// Gaussian splat weights
#define E1f 0.60653065971263342f   // exp(-0.5)
#define E2f 0.13533528323661270f   // exp(-2.0)

// LDS column stride: 132 floats = 528 B = 16*33 -> every column 16B-aligned,
// word bank = (4*w + d) % 32 -> float4 reads across lanes are conflict-free.
#define CSTR 132

// ---------------------------------------------------------------------------
// Kernel 1 (verified round 1): antialiased bilinear resize 512x512 -> 128x128.
// Depth path fp64 (feeds truncation), x-ray path fp32.
// Taps c = 4j-2..4j+5 come from the three ALIGNED float4 blocks at float4
// index j-1, j, j+1 (clamped; OOB taps carry weight 0.0 -> exact no-op).
// ---------------------------------------------------------------------------
__global__ __launch_bounds__(256) void resize_kernel(
    const float* __restrict__ depth, const float* __restrict__ xray,
    int* __restrict__ didx, float* __restrict__ xr)
{
    int idx = blockIdx.x * blockDim.x + threadIdx.x;   // 8*128*128 threads
    int j = idx & (OHW - 1);
    int i = (idx >> 7) & (OHW - 1);
    int b = idx >> 14;

    const double rawd[8] = {0.125, 0.375, 0.625, 0.875, 0.875, 0.625, 0.375, 0.125};

    int r0 = 4 * i - 2, c0 = 4 * j - 2;
    double wr[8], wc[8];
    double sr = 0.0, sc = 0.0;
#pragma unroll
    for (int k = 0; k < 8; ++k) {
        int r = r0 + k;
        wr[k] = (r >= 0 && r < IN_HW) ? rawd[k] : 0.0; sr += wr[k];
        int c = c0 + k;
        wc[k] = (c >= 0 && c < IN_HW) ? rawd[k] : 0.0; sc += wc[k];
    }
    double invd = 1.0 / (sr * sc);
    float  invf = (float)invd;

    // float4-index columns, clamped (safe: OOB taps have zero weight)
    int f0 = j - 1; if (f0 < 0) f0 = 0;
    int f2 = j + 1; if (f2 > (IN_HW / 4) - 1) f2 = (IN_HW / 4) - 1;
    int f1 = j;

    const float4* dbase = (const float4*)(depth + (size_t)b * IN_HW * IN_HW);
    const float4* xbase = (const float4*)(xray  + (size_t)b * IN_HW * IN_HW);

    double accD = 0.0;
    float  accX = 0.f;
#pragma unroll
    for (int k = 0; k < 8; ++k) {
        if (wr[k] == 0.0) continue;          // uniform across the wave (i fixed)
        int r = r0 + k;
        const float4* drow = dbase + (size_t)r * (IN_HW / 4);
        const float4* xrow = xbase + (size_t)r * (IN_HW / 4);
        float4 d0 = drow[f0], d1 = drow[f1], d2 = drow[f2];
        float4 x0 = xrow[f0], x1 = xrow[f1], x2 = xrow[f2];
        // taps l=0..7 -> floats 4j-2..4j+5 = {d0.z,d0.w, d1.xyzw, d2.x,d2.y}
        float dt[8] = {d0.z, d0.w, d1.x, d1.y, d1.z, d1.w, d2.x, d2.y};
        float xt[8] = {x0.z, x0.w, x1.x, x1.y, x1.z, x1.w, x2.x, x2.y};
        double rd = 0.0;
        float  rx = 0.f;
#pragma unroll
        for (int l = 0; l < 8; ++l) {
            rd += wc[l] * (double)dt[l];     // wc==0 on OOB taps -> exact no-op
            rx += (float)wc[l] * xt[l];
        }
        accD += wr[k] * rd;
        accX += (float)wr[k] * rx;
    }
    accD *= invd;
    accX *= invf;

    // nd = depth_r / 100 ; d_idx = trunc(nd * 127), clipped to [0,127]
    double nd = accD * (1.0 / 100.0);
    int di = (int)(nd * 127.0);
    di = min(max(di, 0), VOLD - 1);

    didx[idx] = di;
    xr[idx]   = accX;
}

// ---------------------------------------------------------------------------
// Kernel 2 (round-1 structure, 256 threads/block, verified fastest): one
// block per (b, h). Scatter the 3 h-rows x 130 w-cols (halo) depth-pooled
// 7-tap profiles
//   q(d) = x * sum_{t=d-1..d+1, 0<=t<=127} w(t - d_idx)
// into dense LDS col[w'][d], then out(d, w) = (col[w]+col[w+1]+col[w+2])/27,
// coalesced writes.
//
// Only change vs round 1: the scatter's 21-deep serial read-add-write chain
// (each link ~130 cy LDS latency) is replaced by fire-and-forget ds_add_f32
// atomics (no return value -> no dependency chain; issue-limited). Thread ->
// column ownership and per-address issue order are unchanged, so the sums
// are bit-identical (round 3 measured the same absmax with atomic scatter).
// ---------------------------------------------------------------------------
__global__ __launch_bounds__(256) void splat_pool_kernel(
    const int* __restrict__ didx, const float* __restrict__ xr,
    float* __restrict__ out)
{
    __shared__ __align__(16) float col[130][CSTR];  // 68,640 B

    int t   = threadIdx.x;
    int blk = blockIdx.x;
    int h = blk & (OHW - 1);
    int b = blk >> 7;

    // issue scatter-input loads first (coalesced: lane t -> image col t-1)
    float xv[3]; int dv[3];
    if (t < 130) {
        int wc = t - 1;
#pragma unroll
        for (int r = 0; r < 3; ++r) {
            int hr = h + r - 1;
            xv[r] = 0.f; dv[r] = 1 << 20;   // sentinel: no taps in range
            if (hr >= 0 && hr < OHW && wc >= 0 && wc < OHW) {
                int g = (b * OHW + hr) * OHW + wc;
                xv[r] = xr[g]; dv[r] = didx[g];
            }
        }
    }

    // zero col (flat float4; 130*132 = 17160 = 4290 float4)
    {
        float4* colv = (float4*)&col[0][0];
        for (int k = t; k < (130 * CSTR) / 4; k += 256)
            colv[k] = float4{0.f, 0.f, 0.f, 0.f};
    }
    __syncthreads();

    // scatter: thread t owns LDS column t (t < 130); fire-and-forget atomics
    if (t < 130) {
        // S[o+3] = w(o-1)+w(o)+w(o+1), o = d - d_idx in [-3,3]
        // A: d==0 edge (t=-1 term dropped) ; Z: d==127 edge (t=128 dropped)
        const float S[7] = {E2f, E2f + E1f, E2f + E1f + 1.f, 1.f + 2.f * E1f,
                            1.f + E1f + E2f, E1f + E2f, E2f};
        const float A[7] = {E2f, E2f + E1f, E1f + 1.f, 1.f + E1f,
                            E1f + E2f, E2f, 0.f};
        const float Z[7] = {0.f, E2f, E2f + E1f, 1.f + E1f,
                            1.f + E1f, E1f + E2f, E2f};
        float* c = &col[t][0];
#pragma unroll 1
        for (int r = 0; r < 3; ++r) {
            float x = xv[r];
            int  di = dv[r];
#pragma unroll
            for (int o = -3; o <= 3; ++o) {
                int d = di + o;
                if (d < 0 || d > VOLD - 1) continue;
                float w = S[o + 3];
                if (d == 0)            w = A[o + 3];
                else if (d == VOLD-1)  w = Z[o + 3];
                atomicAdd(&c[d], x * w);     // ds_add_f32, no return, no chain
            }
        }
    }
    __syncthreads();

    // gather 3 w-neighbors with float4 LDS reads; 64 depths per thread
    int w    = t & (OHW - 1);
    int half = t >> 7;
    const float inv27 = 1.f / 27.f;
    const float4* colv = (const float4*)&col[0][0];
    int base = w * (CSTR / 4) + half * 16;       // float4 index of col[w][half*64]
    float* obase = out + ((size_t)(b * VOLD + half * 64) * OHW + h) * OHW + w;
#pragma unroll
    for (int q = 0; q < 16; ++q) {
        float4 a = colv[base + q];
        float4 c1 = colv[base + q + (CSTR / 4)];
        float4 c2 = colv[base + q + 2 * (CSTR / 4)];
        float4 v;
        v.x = (a.x + c1.x + c2.x) * inv27;
        v.y = (a.y + c1.y + c2.y) * inv27;
        v.z = (a.z + c1.z + c2.z) * inv27;
        v.w = (a.w + c1.w + c2.w) * inv27;
        float* o = obase + (size_t)(q * 4) * OHW * OHW;
        o[0 * OHW * OHW] = v.x;
        o[1 * OHW * OHW] = v.y;
        o[2 * OHW * OHW] = v.z;
        o[3 * OHW * OHW] = v.w;
    }
}

extern "C" void kernel_launch(void* const* d_in, const int* in_sizes, int n_in,
                              void* d_out, int out_size, void* d_ws, size_t ws_size,
                              hipStream_t stream)
{
    const float* depth = (const float*)d_in[0];
    const float* xray  = (const float*)d_in[1];
    float* out = (float*)d_out;

    const int NPIX = NB * OHW * OHW;           // 131072
    int*   didx = (int*)d_ws;
    float* xrs  = (float*)((char*)d_ws + (size_t)NPIX * sizeof(int));

    resize_kernel<<<NPIX / 256, 256, 0, stream>>>(depth, xray, didx, xrs);
    splat_pool_kernel<<<NB * OHW, 256, 0, stream>>>(didx, xrs, out);
}

// Round 5
// 96.880 us; speedup vs baseline: 1.0769x; 1.0769x over previous
//
#include <hip/hip_runtime.h>

#define NB 8
#define IN_HW 512
#define OHW 128
#define VOLD 128

// Gaussian splat weights
#define E1f 0.60653065971263342f   // exp(-0.5)
#define E2f 0.13533528323661270f   // exp(-2.0)

// LDS column stride: 132 floats = 528 B = 16*33 -> every column 16B-aligned,
// word bank = (4*w + d) % 32 -> float4 reads across lanes are conflict-free.
#define CSTR 132

// ---------------------------------------------------------------------------
// Kernel 1: antialiased bilinear resize 512x512 -> 128x128 (jax.image.resize
// antialias=True semantics). Depth path fp64 (feeds a truncation -> must be
// as close to exact as possible); x-ray path fp32 (output tolerance 6.4e-3).
// Output pixel i samples input at 4i+1.5, triangle radius 4: taps 4i-2..4i+5,
// raw weights {1,3,5,7,7,5,3,1}/8, renormalized by in-range raw-weight sum.
//
// Taps c = 4j-2..4j+5 are covered by the three ALIGNED float4 blocks at
// float4-index j-1, j, j+1 (floats 4j-4..4j+7). Consecutive lanes -> perfectly
// contiguous 1 KB wave transactions. Edge clamp of the float4 index into
// [0,127] is exact: any tap outside the image has weight 0.0, so the clamped
// (finite) garbage value contributes 0.0 * finite = +0.0, bit-identical to
// skipping it (all accumulators start at +0.0, inputs >= 0).
// ---------------------------------------------------------------------------
__global__ __launch_bounds__(256) void resize_kernel(
    const float* __restrict__ depth, const float* __restrict__ xray,
    int* __restrict__ didx, float* __restrict__ xr)
{
    int idx = blockIdx.x * blockDim.x + threadIdx.x;   // 8*128*128 threads
    int j = idx & (OHW - 1);
    int i = (idx >> 7) & (OHW - 1);
    int b = idx >> 14;

    const double rawd[8] = {0.125, 0.375, 0.625, 0.875, 0.875, 0.625, 0.375, 0.125};

    int r0 = 4 * i - 2, c0 = 4 * j - 2;
    double wr[8], wc[8];
    double sr = 0.0, sc = 0.0;
#pragma unroll
    for (int k = 0; k < 8; ++k) {
        int r = r0 + k;
        wr[k] = (r >= 0 && r < IN_HW) ? rawd[k] : 0.0; sr += wr[k];
        int c = c0 + k;
        wc[k] = (c >= 0 && c < IN_HW) ? rawd[k] : 0.0; sc += wc[k];
    }
    double invd = 1.0 / (sr * sc);
    float  invf = (float)invd;

    // float4-index columns, clamped (safe: OOB taps have zero weight)
    int f0 = j - 1; if (f0 < 0) f0 = 0;
    int f2 = j + 1; if (f2 > (IN_HW / 4) - 1) f2 = (IN_HW / 4) - 1;
    int f1 = j;

    const float4* dbase = (const float4*)(depth + (size_t)b * IN_HW * IN_HW);
    const float4* xbase = (const float4*)(xray  + (size_t)b * IN_HW * IN_HW);

    double accD = 0.0;
    float  accX = 0.f;
#pragma unroll
    for (int k = 0; k < 8; ++k) {
        if (wr[k] == 0.0) continue;          // uniform across the wave (i fixed)
        int r = r0 + k;
        const float4* drow = dbase + (size_t)r * (IN_HW / 4);
        const float4* xrow = xbase + (size_t)r * (IN_HW / 4);
        float4 d0 = drow[f0], d1 = drow[f1], d2 = drow[f2];
        float4 x0 = xrow[f0], x1 = xrow[f1], x2 = xrow[f2];
        // taps l=0..7 -> floats 4j-2..4j+5 = {d0.z,d0.w, d1.xyzw, d2.x,d2.y}
        float dt[8] = {d0.z, d0.w, d1.x, d1.y, d1.z, d1.w, d2.x, d2.y};
        float xt[8] = {x0.z, x0.w, x1.x, x1.y, x1.z, x1.w, x2.x, x2.y};
        double rd = 0.0;
        float  rx = 0.f;
#pragma unroll
        for (int l = 0; l < 8; ++l) {
            rd += wc[l] * (double)dt[l];     // wc==0 on OOB taps -> exact no-op
            rx += (float)wc[l] * xt[l];
        }
        accD += wr[k] * rd;
        accX += (float)wr[k] * rx;
    }
    accD *= invd;
    accX *= invf;

    // nd = depth_r / 100 ; d_idx = trunc(nd * 127), clipped to [0,127]
    double nd = accD * (1.0 / 100.0);
    int di = (int)(nd * 127.0);
    di = min(max(di, 0), VOLD - 1);

    didx[idx] = di;
    xr[idx]   = accX;
}

// ---------------------------------------------------------------------------
// Kernel 2: one block per (b, h). Scatter the 3 h-rows x 130 w-cols (halo)
// depth-pooled 7-tap profiles
//   q(d) = x * sum_{t=d-1..d+1, 0<=t<=127} w(t - d_idx)
// into dense LDS col[w'][d] (summed over the 3 rows), then
// out(d, w) = (col[w] + col[w+1] + col[w+2])(d) / 27, coalesced writes.
// Scatter threads load their (x, didx) pairs from global directly (coalesced
// along w), issued before the zero-fill so latency hides behind it.
// (Serial RMW scatter: measured faster than ds_add_f32 atomics in R4.)
// ---------------------------------------------------------------------------
__global__ __launch_bounds__(256) void splat_pool_kernel(
    const int* __restrict__ didx, const float* __restrict__ xr,
    float* __restrict__ out)
{
    __shared__ __align__(16) float col[130][CSTR];  // 68,640 B

    int t   = threadIdx.x;
    int blk = blockIdx.x;
    int h = blk & (OHW - 1);
    int b = blk >> 7;

    // issue scatter-input loads first (coalesced: lane t -> image col t-1)
    float xv[3]; int dv[3];
    if (t < 130) {
        int wc = t - 1;
#pragma unroll
        for (int r = 0; r < 3; ++r) {
            int hr = h + r - 1;
            xv[r] = 0.f; dv[r] = 1 << 20;   // sentinel: no taps in range
            if (hr >= 0 && hr < OHW && wc >= 0 && wc < OHW) {
                int g = (b * OHW + hr) * OHW + wc;
                xv[r] = xr[g]; dv[r] = didx[g];
            }
        }
    }

    // zero col (flat float4; 130*132 = 17160 = 4290 float4)
    {
        float4* colv = (float4*)&col[0][0];
        for (int k = t; k < (130 * CSTR) / 4; k += 256)
            colv[k] = float4{0.f, 0.f, 0.f, 0.f};
    }
    __syncthreads();

    // scatter: thread t owns LDS column t (t < 130)
    if (t < 130) {
        // S[o+3] = w(o-1)+w(o)+w(o+1), o = d - d_idx in [-3,3]
        // A: d==0 edge (t=-1 term dropped) ; Z: d==127 edge (t=128 dropped)
        const float S[7] = {E2f, E2f + E1f, E2f + E1f + 1.f, 1.f + 2.f * E1f,
                            1.f + E1f + E2f, E1f + E2f, E2f};
        const float A[7] = {E2f, E2f + E1f, E1f + 1.f, 1.f + E1f,
                            E1f + E2f, E2f, 0.f};
        const float Z[7] = {0.f, E2f, E2f + E1f, 1.f + E1f,
                            1.f + E1f, E1f + E2f, E2f};
#pragma unroll 1
        for (int r = 0; r < 3; ++r) {
            float x = xv[r];
            int  di = dv[r];
#pragma unroll
            for (int o = -3; o <= 3; ++o) {
                int d = di + o;
                if (d < 0 || d > VOLD - 1) continue;
                float w = S[o + 3];
                if (d == 0)            w = A[o + 3];
                else if (d == VOLD-1)  w = Z[o + 3];
                col[t][d] += x * w;
            }
        }
    }
    __syncthreads();

    // gather 3 w-neighbors with float4 LDS reads; 64 depths per thread
    int w    = t & (OHW - 1);
    int half = t >> 7;
    const float inv27 = 1.f / 27.f;
    const float4* colv = (const float4*)&col[0][0];
    int base = w * (CSTR / 4) + half * 16;       // float4 index of col[w][half*64]
    float* obase = out + ((size_t)(b * VOLD + half * 64) * OHW + h) * OHW + w;
#pragma unroll
    for (int q = 0; q < 16; ++q) {
        float4 a = colv[base + q];
        float4 c1 = colv[base + q + (CSTR / 4)];
        float4 c2 = colv[base + q + 2 * (CSTR / 4)];
        float4 v;
        v.x = (a.x + c1.x + c2.x) * inv27;
        v.y = (a.y + c1.y + c2.y) * inv27;
        v.z = (a.z + c1.z + c2.z) * inv27;
        v.w = (a.w + c1.w + c2.w) * inv27;
        float* o = obase + (size_t)(q * 4) * OHW * OHW;
        o[0 * OHW * OHW] = v.x;
        o[1 * OHW * OHW] = v.y;
        o[2 * OHW * OHW] = v.z;
        o[3 * OHW * OHW] = v.w;
    }
}

extern "C" void kernel_launch(void* const* d_in, const int* in_sizes, int n_in,
                              void* d_out, int out_size, void* d_ws, size_t ws_size,
                              hipStream_t stream)
{
    const float* depth = (const float*)d_in[0];
    const float* xray  = (const float*)d_in[1];
    float* out = (float*)d_out;

    const int NPIX = NB * OHW * OHW;           // 131072
    int*   didx = (int*)d_ws;
    float* xrs  = (float*)((char*)d_ws + (size_t)NPIX * sizeof(int));

    resize_kernel<<<NPIX / 256, 256, 0, stream>>>(depth, xray, didx, xrs);
    splat_pool_kernel<<<NB * OHW, 256, 0, stream>>>(didx, xrs, out);
}